// Round 1
// baseline (6114.872 us; speedup 1.0000x reference)
//
#include <hip/hip_runtime.h>

#define USER_NUM 200000
#define ITEM_NUM 100000
#define N_NODES  (USER_NUM + ITEM_NUM)
#define EMB      64
#define NNZ      9600000

// ---------------------------------------------------------------------------
// init: ego = concat(user_emb, item_emb); out(acc) = ego; Y = 0
// ---------------------------------------------------------------------------
__global__ __launch_bounds__(256) void init_kernel(
    const float* __restrict__ user_emb,
    const float* __restrict__ item_emb,
    float* __restrict__ X,
    float* __restrict__ Y,
    float* __restrict__ out) {
  const long total4 = (long)N_NODES * EMB / 4;   // 4.8M float4
  long g = (long)blockIdx.x * blockDim.x + threadIdx.x;
  if (g >= total4) return;
  const long user4 = (long)USER_NUM * EMB / 4;
  float4 v;
  if (g < user4) v = ((const float4*)user_emb)[g];
  else           v = ((const float4*)item_emb)[g - user4];
  ((float4*)X)[g]   = v;
  ((float4*)out)[g] = v;
  ((float4*)Y)[g]   = make_float4(0.f, 0.f, 0.f, 0.f);
}

// ---------------------------------------------------------------------------
// COO SpMM: y[rows[e], :] += vals[e] * x[cols[e], :]
// one wave per edge (64 lanes = 64 emb dims), U=4 edges per chunk for MLP +
// merged s_load_dwordx4 on the index arrays.
// ---------------------------------------------------------------------------
__global__ __launch_bounds__(256) void spmm_kernel(
    const float* __restrict__ vals,
    const int*   __restrict__ rows,
    const int*   __restrict__ cols,
    const float* __restrict__ x,
    float*       __restrict__ y) {
  const int lane = threadIdx.x & 63;
  int wave = blockIdx.x * (blockDim.x >> 6) + (threadIdx.x >> 6);
  wave = __builtin_amdgcn_readfirstlane(wave);          // SGPR wave id
  const int nwaves = gridDim.x * (blockDim.x >> 6);
  constexpr int U = 4;                                   // NNZ % 4 == 0

  for (long base = (long)wave * U; base < NNZ; base += (long)nwaves * U) {
    int r[U], c[U];
    float v[U];
#pragma unroll
    for (int u = 0; u < U; ++u) {
      r[u] = rows[base + u];    // uniform (SGPR) address -> s_load
      c[u] = cols[base + u];
      v[u] = vals[base + u];
    }
#pragma unroll
    for (int u = 0; u < U; ++u) {
      float xv = x[(long)c[u] * EMB + lane];             // coalesced 256B gather
      unsafeAtomicAdd(&y[(long)r[u] * EMB + lane], v[u] * xv);  // hw f32 atomic
    }
  }
}

// ---------------------------------------------------------------------------
// out += S; Z = 0   (Z is the ping-pong buffer the next spmm writes into)
// ---------------------------------------------------------------------------
__global__ __launch_bounds__(256) void add_zero_kernel(
    float* __restrict__ out,
    const float* __restrict__ S,
    float* __restrict__ Z) {
  const long total4 = (long)N_NODES * EMB / 4;
  long g = (long)blockIdx.x * blockDim.x + threadIdx.x;
  if (g >= total4) return;
  float4 a = ((float4*)out)[g];
  float4 s = ((const float4*)S)[g];
  a.x += s.x; a.y += s.y; a.z += s.z; a.w += s.w;
  ((float4*)out)[g] = a;
  ((float4*)Z)[g]   = make_float4(0.f, 0.f, 0.f, 0.f);
}

// ---------------------------------------------------------------------------
// out = (out + S) * 0.25
// ---------------------------------------------------------------------------
__global__ __launch_bounds__(256) void final_kernel(
    float* __restrict__ out,
    const float* __restrict__ S) {
  const long total4 = (long)N_NODES * EMB / 4;
  long g = (long)blockIdx.x * blockDim.x + threadIdx.x;
  if (g >= total4) return;
  float4 a = ((float4*)out)[g];
  float4 s = ((const float4*)S)[g];
  a.x = (a.x + s.x) * 0.25f;
  a.y = (a.y + s.y) * 0.25f;
  a.z = (a.z + s.z) * 0.25f;
  a.w = (a.w + s.w) * 0.25f;
  ((float4*)out)[g] = a;
}

extern "C" void kernel_launch(void* const* d_in, const int* in_sizes, int n_in,
                              void* d_out, int out_size, void* d_ws, size_t ws_size,
                              hipStream_t stream) {
  const float* user_emb = (const float*)d_in[0];
  const float* item_emb = (const float*)d_in[1];
  const float* adj_vals = (const float*)d_in[2];
  const int*   adj_rows = (const int*)d_in[3];
  const int*   adj_cols = (const int*)d_in[4];
  float* out = (float*)d_out;

  float* X = (float*)d_ws;                       // 76.8 MB
  float* Y = X + (long)N_NODES * EMB;            // 76.8 MB

  const long total4 = (long)N_NODES * EMB / 4;
  const int ew_blocks = (int)((total4 + 255) / 256);
  const int spmm_blocks = 2048;                  // 8 blocks/CU * 256 CU

  // acc = x0 = ego; Y = 0
  init_kernel<<<ew_blocks, 256, 0, stream>>>(user_emb, item_emb, X, Y, out);
  // layer 1: Y = A x0 ; acc += Y ; X = 0
  spmm_kernel<<<spmm_blocks, 256, 0, stream>>>(adj_vals, adj_rows, adj_cols, X, Y);
  add_zero_kernel<<<ew_blocks, 256, 0, stream>>>(out, Y, X);
  // layer 2: X = A x1 ; acc += X ; Y = 0
  spmm_kernel<<<spmm_blocks, 256, 0, stream>>>(adj_vals, adj_rows, adj_cols, Y, X);
  add_zero_kernel<<<ew_blocks, 256, 0, stream>>>(out, X, Y);
  // layer 3: Y = A x2 ; acc = (acc + Y) / 4
  spmm_kernel<<<spmm_blocks, 256, 0, stream>>>(adj_vals, adj_rows, adj_cols, X, Y);
  final_kernel<<<ew_blocks, 256, 0, stream>>>(out, Y);
}

// Round 2
// 2363.164 us; speedup vs baseline: 2.5876x; 2.5876x over previous
//
#include <hip/hip_runtime.h>

#define USER_NUM 200000
#define ITEM_NUM 100000
#define N_NODES  (USER_NUM + ITEM_NUM)
#define EMB      64
#define NNZ      9600000
#define NBLK_SCAN ((N_NODES + 255) / 256)   // 1172

// ===========================================================================
// Fast path: per-call counting-sort -> CSR -> atomic-free SpMM
// ===========================================================================

// init: X = concat(user_emb, item_emb); out = X
__global__ __launch_bounds__(256) void init_nodes_kernel(
    const float* __restrict__ user_emb,
    const float* __restrict__ item_emb,
    float* __restrict__ X,
    float* __restrict__ out) {
  const long total4 = (long)N_NODES * EMB / 4;
  long g = (long)blockIdx.x * blockDim.x + threadIdx.x;
  if (g >= total4) return;
  const long user4 = (long)USER_NUM * EMB / 4;
  float4 v;
  if (g < user4) v = ((const float4*)user_emb)[g];
  else           v = ((const float4*)item_emb)[g - user4];
  ((float4*)X)[g]   = v;
  ((float4*)out)[g] = v;
}

__global__ __launch_bounds__(256) void zero_cnt_kernel(int* __restrict__ cnt) {
  int i = blockIdx.x * 256 + threadIdx.x;
  if (i < N_NODES) cnt[i] = 0;
}

// histogram of destination rows (4 edges / thread, int4 loads)
__global__ __launch_bounds__(256) void hist_kernel(
    const int* __restrict__ rows, int* __restrict__ cnt) {
  int t = blockIdx.x * 256 + threadIdx.x;     // t < NNZ/4 exactly
  int4 r = ((const int4*)rows)[t];
  atomicAdd(&cnt[r.x], 1);
  atomicAdd(&cnt[r.y], 1);
  atomicAdd(&cnt[r.z], 1);
  atomicAdd(&cnt[r.w], 1);
}

// block-level exclusive scan of cnt -> off (partial), block totals -> bsum
__global__ __launch_bounds__(256) void scan1_kernel(
    const int* __restrict__ cnt, int* __restrict__ off, int* __restrict__ bsum) {
  __shared__ int sh[256];
  int tid = threadIdx.x;
  int i = blockIdx.x * 256 + tid;
  int v = (i < N_NODES) ? cnt[i] : 0;
  sh[tid] = v; __syncthreads();
#pragma unroll
  for (int ofs = 1; ofs < 256; ofs <<= 1) {
    int t = (tid >= ofs) ? sh[tid - ofs] : 0;
    __syncthreads();
    sh[tid] += t;
    __syncthreads();
  }
  if (i < N_NODES) off[i] = sh[tid] - v;       // exclusive within block
  if (tid == 255) bsum[blockIdx.x] = sh[255];  // block total
}

// single-block exclusive scan of the 1172 block sums (chunked, carried)
__global__ __launch_bounds__(256) void scan2_kernel(int* __restrict__ bsum) {
  __shared__ int sh[256];
  __shared__ int carry_sh;
  int tid = threadIdx.x;
  if (tid == 0) carry_sh = 0;
  __syncthreads();
  for (int base = 0; base < NBLK_SCAN; base += 256) {
    int idx = base + tid;
    int v = (idx < NBLK_SCAN) ? bsum[idx] : 0;
    sh[tid] = v; __syncthreads();
#pragma unroll
    for (int ofs = 1; ofs < 256; ofs <<= 1) {
      int t = (tid >= ofs) ? sh[tid - ofs] : 0;
      __syncthreads();
      sh[tid] += t;
      __syncthreads();
    }
    int incl  = sh[tid];
    int carry = carry_sh;
    if (idx < NBLK_SCAN) bsum[idx] = carry + incl - v;   // exclusive
    int total = sh[255];
    __syncthreads();
    if (tid == 0) carry_sh = carry + total;
    __syncthreads();
  }
}

// off[i] += bsum[block]; cur = off; off[N_NODES] = NNZ
__global__ __launch_bounds__(256) void scan3_kernel(
    int* __restrict__ off, const int* __restrict__ bsum, int* __restrict__ cur) {
  int i = blockIdx.x * 256 + threadIdx.x;
  if (i < N_NODES) {
    int o = off[i] + bsum[blockIdx.x];
    off[i] = o;
    cur[i] = o;
  }
  if (i == 0) off[N_NODES] = NNZ;
}

// scatter edges into row-sorted (col,val) pairs
__global__ __launch_bounds__(256) void scatter_kernel(
    const int* __restrict__ rows, const int* __restrict__ cols,
    const float* __restrict__ vals, int* __restrict__ cur,
    int2* __restrict__ CV) {
  int t = blockIdx.x * 256 + threadIdx.x;     // t < NNZ/4 exactly
  int4   r = ((const int4*)rows)[t];
  int4   c = ((const int4*)cols)[t];
  float4 v = ((const float4*)vals)[t];
  int p;
  p = atomicAdd(&cur[r.x], 1); CV[p] = make_int2(c.x, __float_as_int(v.x));
  p = atomicAdd(&cur[r.y], 1); CV[p] = make_int2(c.y, __float_as_int(v.y));
  p = atomicAdd(&cur[r.z], 1); CV[p] = make_int2(c.z, __float_as_int(v.z));
  p = atomicAdd(&cur[r.w], 1); CV[p] = make_int2(c.w, __float_as_int(v.w));
}

// CSR SpMM, wave per row, no atomics. Fused layer accumulation.
// FINAL==0: y = A*x ; out += y      FINAL==1: out = (out + A*x) * 0.25
template <int FINAL>
__global__ __launch_bounds__(256) void spmm_csr_kernel(
    const int*  __restrict__ off, const int2* __restrict__ CV,
    const float* __restrict__ x, float* __restrict__ y,
    float* __restrict__ out) {
  const int lane = threadIdx.x & 63;
  int wid = blockIdx.x * (blockDim.x >> 6) + (threadIdx.x >> 6);
  const int nw = gridDim.x * (blockDim.x >> 6);
  for (int r = wid; r < N_NODES; r += nw) {
    int s = __builtin_amdgcn_readfirstlane(off[r]);
    int e = __builtin_amdgcn_readfirstlane(off[r + 1]);
    float acc = 0.f;
    int i = s;
    for (; i + 4 <= e; i += 4) {
      int2 a = CV[i], b = CV[i + 1], c = CV[i + 2], d = CV[i + 3];
      acc += __int_as_float(a.y) * x[a.x * EMB + lane];
      acc += __int_as_float(b.y) * x[b.x * EMB + lane];
      acc += __int_as_float(c.y) * x[c.x * EMB + lane];
      acc += __int_as_float(d.y) * x[d.x * EMB + lane];
    }
    for (; i < e; ++i) {
      int2 a = CV[i];
      acc += __int_as_float(a.y) * x[a.x * EMB + lane];
    }
    int o = r * EMB + lane;
    if (FINAL) {
      out[o] = (out[o] + acc) * 0.25f;
    } else {
      y[o] = acc;
      out[o] += acc;
    }
  }
}

// ===========================================================================
// Fallback path (round-1 atomic version) if ws_size is too small
// ===========================================================================
__global__ __launch_bounds__(256) void init_kernel_fb(
    const float* __restrict__ user_emb, const float* __restrict__ item_emb,
    float* __restrict__ X, float* __restrict__ Y, float* __restrict__ out) {
  const long total4 = (long)N_NODES * EMB / 4;
  long g = (long)blockIdx.x * blockDim.x + threadIdx.x;
  if (g >= total4) return;
  const long user4 = (long)USER_NUM * EMB / 4;
  float4 v;
  if (g < user4) v = ((const float4*)user_emb)[g];
  else           v = ((const float4*)item_emb)[g - user4];
  ((float4*)X)[g]   = v;
  ((float4*)out)[g] = v;
  ((float4*)Y)[g]   = make_float4(0.f, 0.f, 0.f, 0.f);
}

__global__ __launch_bounds__(256) void spmm_atomic_kernel_fb(
    const float* __restrict__ vals, const int* __restrict__ rows,
    const int* __restrict__ cols, const float* __restrict__ x,
    float* __restrict__ y) {
  const int lane = threadIdx.x & 63;
  int wave = blockIdx.x * (blockDim.x >> 6) + (threadIdx.x >> 6);
  wave = __builtin_amdgcn_readfirstlane(wave);
  const int nwaves = gridDim.x * (blockDim.x >> 6);
  constexpr int U = 4;
  for (long base = (long)wave * U; base < NNZ; base += (long)nwaves * U) {
    int r[U], c[U]; float v[U];
#pragma unroll
    for (int u = 0; u < U; ++u) { r[u] = rows[base+u]; c[u] = cols[base+u]; v[u] = vals[base+u]; }
#pragma unroll
    for (int u = 0; u < U; ++u) {
      float xv = x[(long)c[u] * EMB + lane];
      unsafeAtomicAdd(&y[(long)r[u] * EMB + lane], v[u] * xv);
    }
  }
}

__global__ __launch_bounds__(256) void add_zero_kernel_fb(
    float* __restrict__ out, const float* __restrict__ S, float* __restrict__ Z) {
  const long total4 = (long)N_NODES * EMB / 4;
  long g = (long)blockIdx.x * blockDim.x + threadIdx.x;
  if (g >= total4) return;
  float4 a = ((float4*)out)[g];
  float4 s = ((const float4*)S)[g];
  a.x += s.x; a.y += s.y; a.z += s.z; a.w += s.w;
  ((float4*)out)[g] = a;
  ((float4*)Z)[g]   = make_float4(0.f, 0.f, 0.f, 0.f);
}

__global__ __launch_bounds__(256) void final_kernel_fb(
    float* __restrict__ out, const float* __restrict__ S) {
  const long total4 = (long)N_NODES * EMB / 4;
  long g = (long)blockIdx.x * blockDim.x + threadIdx.x;
  if (g >= total4) return;
  float4 a = ((float4*)out)[g];
  float4 s = ((const float4*)S)[g];
  a.x = (a.x + s.x) * 0.25f; a.y = (a.y + s.y) * 0.25f;
  a.z = (a.z + s.z) * 0.25f; a.w = (a.w + s.w) * 0.25f;
  ((float4*)out)[g] = a;
}

// ===========================================================================
extern "C" void kernel_launch(void* const* d_in, const int* in_sizes, int n_in,
                              void* d_out, int out_size, void* d_ws, size_t ws_size,
                              hipStream_t stream) {
  const float* user_emb = (const float*)d_in[0];
  const float* item_emb = (const float*)d_in[1];
  const float* adj_vals = (const float*)d_in[2];
  const int*   adj_rows = (const int*)d_in[3];
  const int*   adj_cols = (const int*)d_in[4];
  float* out = (float*)d_out;

  const size_t nodeF = (size_t)N_NODES * EMB;          // 19.2M floats
  const long total4 = (long)N_NODES * EMB / 4;
  const int ew_blocks   = (int)((total4 + 255) / 256);
  const int edge_blocks = NNZ / 4 / 256;               // 9375, exact
  const int node_blocks = NBLK_SCAN;                   // 1172

  // ws layout (fast path): X | Y | CV | off | cur | bsum
  float* X   = (float*)d_ws;
  float* Y   = X + nodeF;
  int2*  CV  = (int2*)(Y + nodeF);
  int*   off = (int*)(CV + NNZ);
  int*   cur = off + (N_NODES + 1);
  int*   bsum = cur + N_NODES;
  const size_t need = 2 * nodeF * sizeof(float) + (size_t)NNZ * 8 +
                      (size_t)(2 * N_NODES + 1 + NBLK_SCAN) * sizeof(int);

  if (ws_size >= need) {
    // ---- fast path ----
    init_nodes_kernel<<<ew_blocks, 256, 0, stream>>>(user_emb, item_emb, X, out);
    zero_cnt_kernel<<<node_blocks, 256, 0, stream>>>(cur);   // cur doubles as cnt
    hist_kernel<<<edge_blocks, 256, 0, stream>>>(adj_rows, cur);
    scan1_kernel<<<node_blocks, 256, 0, stream>>>(cur, off, bsum);
    scan2_kernel<<<1, 256, 0, stream>>>(bsum);
    scan3_kernel<<<node_blocks, 256, 0, stream>>>(off, bsum, cur);
    scatter_kernel<<<edge_blocks, 256, 0, stream>>>(adj_rows, adj_cols, adj_vals, cur, CV);
    const int spmm_blocks = 2048;
    spmm_csr_kernel<0><<<spmm_blocks, 256, 0, stream>>>(off, CV, X, Y, out);
    spmm_csr_kernel<0><<<spmm_blocks, 256, 0, stream>>>(off, CV, Y, X, out);
    spmm_csr_kernel<1><<<spmm_blocks, 256, 0, stream>>>(off, CV, X, Y, out);
  } else {
    // ---- fallback: round-1 atomic path ----
    float* Xf = (float*)d_ws;
    float* Yf = Xf + nodeF;
    const int spmm_blocks = 2048;
    init_kernel_fb<<<ew_blocks, 256, 0, stream>>>(user_emb, item_emb, Xf, Yf, out);
    spmm_atomic_kernel_fb<<<spmm_blocks, 256, 0, stream>>>(adj_vals, adj_rows, adj_cols, Xf, Yf);
    add_zero_kernel_fb<<<ew_blocks, 256, 0, stream>>>(out, Yf, Xf);
    spmm_atomic_kernel_fb<<<spmm_blocks, 256, 0, stream>>>(adj_vals, adj_rows, adj_cols, Yf, Xf);
    add_zero_kernel_fb<<<ew_blocks, 256, 0, stream>>>(out, Xf, Yf);
    spmm_atomic_kernel_fb<<<spmm_blocks, 256, 0, stream>>>(adj_vals, adj_rows, adj_cols, Xf, Yf);
    final_kernel_fb<<<ew_blocks, 256, 0, stream>>>(out, Yf);
  }
}